// Round 18
// baseline (223.881 us; speedup 1.0000x reference)
//
#include <hip/hip_runtime.h>
#include <cstdint>

typedef unsigned short u16;
using bf16x8 = __attribute__((ext_vector_type(8))) short;   // 8 bf16 = 4 VGPR
using f32x4  = __attribute__((ext_vector_type(4))) float;   // MFMA acc

struct alignas(16) V16 { uint32_t a, b, c, d; };            // 16B chunk
struct alignas(8)  U16x4 { u16 a, b, c, d; };
struct alignas(16) F4 { float x, y, z, w; };

__device__ __forceinline__ u16 f2bf(float f) {              // RNE f32->bf16
  uint32_t u = __float_as_uint(f);
  u += 0x7fffu + ((u >> 16) & 1u);
  return (u16)(u >> 16);
}
__device__ __forceinline__ float bf2f(u16 h) {
  return __uint_as_float(((uint32_t)h) << 16);
}

// async global->LDS, 16B per lane; dest = wave-uniform base + lane*16 (linear)
#define GLOAD16(g, l) __builtin_amdgcn_global_load_lds(                         \
    (const __attribute__((address_space(1))) uint32_t*)(g),                     \
    (__attribute__((address_space(3))) uint32_t*)(l), 16, 0, 0)

// ===========================================================================
// 2-blocks/CU conv2d GEMM (r18): 256 thr = 4 waves (2M x 2N), BM=192,
// BN=128, BK=64 slab, per-wave 96x64 (acc[6][4]) -- IDENTICAL per-wave
// geometry to r16; single variable = co-residency. LDS ring-2 =
// 2 x (A 24KB + B 16KB) = 80 KiB -> 2 blocks/CU (160 exact). m114:
// co-resident blocks have independent barriers -> while one block drains
// vmcnt(0)+barrier, the other's MFMAs issue. Grid 4x32x8 = 1024 = 2 exact
// rounds. Fence-free interleave + T5 setprio (r16 protocol).
// Swizzle: 128-B rows, chunk ^= (row&7), source+read side; dest linear.
// ===========================================================================
template<int MODE>
__global__ __launch_bounds__(256, 2) void gemm2b_bf16(
    const u16* __restrict__ A, const u16* __restrict__ B, u16* __restrict__ otr,
    int sA, int sB, int64_t bBatch, int trStride, int64_t trBatch, int MT,
    const u16* __restrict__ zpage)
{
  constexpr int NS = (MODE == 2) ? 36 : 12;    // BK=64 slabs
  constexpr int ASL = 12288;                   // A slab u16 (192*64)
  constexpr int BSL = 8192;                    // B slab u16 (128*64)
  constexpr int SLAB = ASL + BSL;              // 20480 u16 = 40 KiB
  __shared__ __align__(16) u16 lds[2 * SLAB];  // 80 KiB

  const int tid = threadIdx.x;
  const int q = gridDim.x >> 3;                // XCD-aware bijective swizzle
  const int flat = (blockIdx.x & 7) * q + (blockIdx.x >> 3);
  const int per_b = MT * 32;                   // 32 n-tiles of 128
  const int b = flat / per_b, rem = flat % per_b;
  const int ntile = rem / MT, mtile = rem % MT;
  const int m0 = mtile * 192, n0 = ntile * 128;
  const u16* Bb = B + (int64_t)b * bBatch;

  const int lane = tid & 63, wave = tid >> 6;
  const int wm = wave >> 1, wn = wave & 1;     // 2M x 2N waves, 96x64 each
  const int lr = lane & 15, lc = lane >> 4;

  const int srow = tid >> 3;                   // 0..31 (row base, +j*32)
  const int sch  = lane & 7;
  const int scs  = sch ^ (srow & 7);           // (srow+32j)&7 == srow&7
  const u16* aSrc[6];
  const u16* bSrc[4];
  int bRow[4];
#pragma unroll
  for (int j = 0; j < 6; ++j)
    aSrc[j] = A + (int64_t)(m0 + srow + j * 32) * sA + scs * 8;
#pragma unroll
  for (int j = 0; j < 4; ++j) {
    bRow[j] = n0 + srow + j * 32;
    bSrc[j] = Bb + (int64_t)bRow[j] * sB + scs * 8;
  }

  auto stageA = [&](int s) {                   // 6 loads/thread
    const int kOff = (s >> 2) * 256 + ((s & 3) << 6);
    u16* dst = lds + (s & 1) * SLAB + wave * 512;
#pragma unroll
    for (int j = 0; j < 6; ++j)
      GLOAD16(aSrc[j] + kOff, dst + j * 2048);
  };
  auto stageB = [&](int s) {                   // 4 loads/thread (tap-masked)
    const int tap = s >> 2, kc = (s & 3) << 6;
    int off, dh = 0, dw = 0;
    if constexpr (MODE == 2) { dh = tap / 3 - 1; dw = tap % 3 - 1; off = dh * 64 + dw; }
    else                     { off = tap - 1; }
    u16* dst = lds + (s & 1) * SLAB + ASL + wave * 512;
#pragma unroll
    for (int j = 0; j < 4; ++j) {
      bool ok;
      if constexpr (MODE == 2) {
        int hh = (bRow[j] >> 6) + dh, ww = (bRow[j] & 63) + dw;
        ok = ((unsigned)hh < 64u) && ((unsigned)ww < 64u);
      } else {
        ok = ((unsigned)(bRow[j] + off) < 4096u);
      }
      const u16* src = ok ? (bSrc[j] + (int64_t)off * sB + kc) : zpage;
      GLOAD16(src, dst + j * 2048);
    }
  };

  f32x4 acc[6][4];
#pragma unroll
  for (int i = 0; i < 6; ++i)
#pragma unroll
    for (int j = 0; j < 4; ++j) acc[i][j] = f32x4{0.f, 0.f, 0.f, 0.f};

  stageA(0); stageB(0); stageA(1); stageB(1);
  asm volatile("s_waitcnt vmcnt(10)" ::: "memory");   // slab 0 landed
  __builtin_amdgcn_s_barrier();
  __builtin_amdgcn_sched_barrier(0);

  for (int s = 0; s < NS; ++s) {
    const u16* As = lds + (s & 1) * SLAB;
    const u16* Bs = As + ASL;
    const bool pf = (s + 1 < NS);
    bf16x8 bfr[4], af[6];

    // ---- k-half 0: reads + stage A(s+1) + 24 MFMA (T5) ----
#pragma unroll
    for (int nf = 0; nf < 4; ++nf) {
      int row = wn * 64 + nf * 16 + lr;
      bfr[nf] = *(const bf16x8*)&Bs[row * 64 + ((lc ^ (row & 7)) * 8)];
    }
#pragma unroll
    for (int mf = 0; mf < 6; ++mf) {
      int row = wm * 96 + mf * 16 + lr;
      af[mf] = *(const bf16x8*)&As[row * 64 + ((lc ^ (row & 7)) * 8)];
    }
    if (pf) stageA(s + 1);
    __builtin_amdgcn_s_setprio(1);
#pragma unroll
    for (int mf = 0; mf < 6; ++mf)
#pragma unroll
      for (int nf = 0; nf < 4; ++nf)
        acc[mf][nf] = __builtin_amdgcn_mfma_f32_16x16x32_bf16(af[mf], bfr[nf], acc[mf][nf], 0, 0, 0);
    __builtin_amdgcn_s_setprio(0);

    // ---- k-half 1: reads + stage B(s+1) + 24 MFMA (T5) ----
#pragma unroll
    for (int nf = 0; nf < 4; ++nf) {
      int row = wn * 64 + nf * 16 + lr;
      bfr[nf] = *(const bf16x8*)&Bs[row * 64 + (((4 + lc) ^ (row & 7)) * 8)];
    }
#pragma unroll
    for (int mf = 0; mf < 6; ++mf) {
      int row = wm * 96 + mf * 16 + lr;
      af[mf] = *(const bf16x8*)&As[row * 64 + (((4 + lc) ^ (row & 7)) * 8)];
    }
    if (pf) stageB(s + 1);
    __builtin_amdgcn_s_setprio(1);
#pragma unroll
    for (int mf = 0; mf < 6; ++mf)
#pragma unroll
      for (int nf = 0; nf < 4; ++nf)
        acc[mf][nf] = __builtin_amdgcn_mfma_f32_16x16x32_bf16(af[mf], bfr[nf], acc[mf][nf], 0, 0, 0);
    __builtin_amdgcn_s_setprio(0);

    if (pf) {
      asm volatile("s_waitcnt vmcnt(0)" ::: "memory");
      __builtin_amdgcn_s_barrier();
      __builtin_amdgcn_sched_barrier(0);
    }
  }

  // epilogue: C/D layout col=lane&15, row=(lane>>4)*4+reg; write transposed
#pragma unroll
  for (int mf = 0; mf < 6; ++mf)
#pragma unroll
    for (int nf = 0; nf < 4; ++nf) {
      f32x4 v = acc[mf][nf];
      int m = m0 + wm * 96 + mf * 16 + lc * 4;
      int n = n0 + wn * 64 + nf * 16 + lr;
      U16x4 pk{f2bf(v[0]), f2bf(v[1]), f2bf(v[2]), f2bf(v[3])};
      *(U16x4*)(otr + trBatch * b + (int64_t)n * trStride + m) = pk;
    }
}

// ===========================================================================
// r16 conv-GEMM (8 waves, ring-2, fence-free + T5) -- used for conv1d+FUSE.
// ===========================================================================
template<int MODE, int MF, int FUSE = 0>
__global__ __launch_bounds__(512, 2) void gemmOv_bf16(
    const u16* __restrict__ A, const u16* __restrict__ B, u16* __restrict__ otr,
    int sA, int sB, int64_t bBatch, int trStride, int64_t trBatch, int MT,
    const u16* __restrict__ zpage,
    const u16* __restrict__ fq = nullptr, u16* __restrict__ eOut = nullptr,
    float* __restrict__ partS = nullptr)
{
  constexpr int NS = (MODE == 2) ? 36 : 12;
  constexpr int ASL = MF * 2048;
  constexpr int SLAB = ASL + 16384;
  __shared__ __align__(16) u16 lds[2 * SLAB];

  const int tid = threadIdx.x;
  const int q = gridDim.x >> 3;
  const int flat = (blockIdx.x & 7) * q + (blockIdx.x >> 3);
  const int per_b = MT * 16;
  const int b = flat / per_b, rem = flat % per_b;
  const int ntile = rem / MT, mtile = rem % MT;
  const int m0 = mtile * (MF * 32), n0 = ntile * 256;
  const u16* Bb = B + (int64_t)b * bBatch;

  const int lane = tid & 63, wave = tid >> 6;
  const int wm = wave >> 2, wn = wave & 3;
  const int lr = lane & 15, lc = lane >> 4;

  const int lrow8 = lane >> 3;
  const int sch  = lane & 7;
  const int scs  = sch ^ (lrow8 & 7);
  const u16* aSrc[MF / 2];
  const u16* bSrc[4];
  int bRow[4];
#pragma unroll
  for (int j = 0; j < MF / 2; ++j)
    aSrc[j] = A + (int64_t)(m0 + wave * (MF * 4) + j * 8 + lrow8) * sA + scs * 8;
#pragma unroll
  for (int j = 0; j < 4; ++j) {
    bRow[j] = n0 + wave * 32 + j * 8 + lrow8;
    bSrc[j] = Bb + (int64_t)bRow[j] * sB + scs * 8;
  }

  auto stageA = [&](int s) {
    const int kOff = (s >> 2) * 256 + ((s & 3) << 6);
    u16* dst = lds + (s & 1) * SLAB + wave * (MF / 2) * 512;
#pragma unroll
    for (int j = 0; j < MF / 2; ++j)
      GLOAD16(aSrc[j] + kOff, dst + j * 512);
  };
  auto stageB = [&](int s) {
    const int tap = s >> 2, kc = (s & 3) << 6;
    int off, dh = 0, dw = 0;
    if constexpr (MODE == 2) { dh = tap / 3 - 1; dw = tap % 3 - 1; off = dh * 64 + dw; }
    else                     { off = tap - 1; }
    u16* dst = lds + (s & 1) * SLAB + ASL + wave * 2048;
#pragma unroll
    for (int j = 0; j < 4; ++j) {
      bool ok;
      if constexpr (MODE == 2) {
        int hh = (bRow[j] >> 6) + dh, ww = (bRow[j] & 63) + dw;
        ok = ((unsigned)hh < 64u) && ((unsigned)ww < 64u);
      } else {
        ok = ((unsigned)(bRow[j] + off) < 4096u);
      }
      const u16* src = ok ? (bSrc[j] + (int64_t)off * sB + kc) : zpage;
      GLOAD16(src, dst + j * 512);
    }
  };

  f32x4 acc[MF][4];
#pragma unroll
  for (int i = 0; i < MF; ++i)
#pragma unroll
    for (int j = 0; j < 4; ++j) acc[i][j] = f32x4{0.f, 0.f, 0.f, 0.f};

  stageA(0); stageB(0);
  asm volatile("s_waitcnt vmcnt(0)" ::: "memory");
  __builtin_amdgcn_s_barrier();
  __builtin_amdgcn_sched_barrier(0);

  for (int s = 0; s < NS; ++s) {
    const u16* As = lds + (s & 1) * SLAB;
    const u16* Bs = As + ASL;
    const bool pf = (s + 1 < NS);
    bf16x8 bfr[4], af[MF];

#pragma unroll
    for (int nf = 0; nf < 4; ++nf) {
      int row = wn * 64 + nf * 16 + lr;
      bfr[nf] = *(const bf16x8*)&Bs[row * 64 + ((lc ^ (row & 7)) * 8)];
    }
#pragma unroll
    for (int mf = 0; mf < MF; ++mf) {
      int row = wm * (MF * 16) + mf * 16 + lr;
      af[mf] = *(const bf16x8*)&As[row * 64 + ((lc ^ (row & 7)) * 8)];
    }
    if (pf) stageA(s + 1);
    __builtin_amdgcn_s_setprio(1);
#pragma unroll
    for (int mf = 0; mf < MF; ++mf)
#pragma unroll
      for (int nf = 0; nf < 4; ++nf)
        acc[mf][nf] = __builtin_amdgcn_mfma_f32_16x16x32_bf16(af[mf], bfr[nf], acc[mf][nf], 0, 0, 0);
    __builtin_amdgcn_s_setprio(0);

#pragma unroll
    for (int nf = 0; nf < 4; ++nf) {
      int row = wn * 64 + nf * 16 + lr;
      bfr[nf] = *(const bf16x8*)&Bs[row * 64 + (((4 + lc) ^ (row & 7)) * 8)];
    }
#pragma unroll
    for (int mf = 0; mf < MF; ++mf) {
      int row = wm * (MF * 16) + mf * 16 + lr;
      af[mf] = *(const bf16x8*)&As[row * 64 + (((4 + lc) ^ (row & 7)) * 8)];
    }
    if (pf) stageB(s + 1);
    __builtin_amdgcn_s_setprio(1);
#pragma unroll
    for (int mf = 0; mf < MF; ++mf)
#pragma unroll
      for (int nf = 0; nf < 4; ++nf)
        acc[mf][nf] = __builtin_amdgcn_mfma_f32_16x16x32_bf16(af[mf], bfr[nf], acc[mf][nf], 0, 0, 0);
    __builtin_amdgcn_s_setprio(0);

    if (pf) {
      asm volatile("s_waitcnt vmcnt(0)" ::: "memory");
      __builtin_amdgcn_s_barrier();
      __builtin_amdgcn_sched_barrier(0);
    }
  }

  if constexpr (FUSE) {
    const u16* qk = fq + (int64_t)b * 4096 * 768;
    u16* eb = eOut + (int64_t)b * 512 * 4096;
    float* ps = partS + (int64_t)b * 512 * 64;
#pragma unroll
    for (int mf = 0; mf < MF; ++mf) {
      const int mbase = m0 + wm * (MF * 16) + mf * 16 + lc * 4;
      float sp[4] = {0.f, 0.f, 0.f, 0.f};
#pragma unroll
      for (int nf = 0; nf < 4; ++nf) {
        int n = n0 + wn * 64 + nf * 16 + lr;
        U16x4 qv = *(const U16x4*)(qk + (int64_t)n * 768 + mbase);
        const u16* qp = (const u16*)&qv;
        f32x4 v = acc[mf][nf];
#pragma unroll
        for (int r = 0; r < 4; ++r) {
          float z = bf2f(qp[r]) * v[r];
          float e = __expf(z > 0.f ? -z : 0.f);
          sp[r] += e;
          eb[(int64_t)(mbase + r) * 4096 + n] = f2bf(e);
        }
      }
#pragma unroll
      for (int r = 0; r < 4; ++r) {
        float sv = sp[r];
        sv += __shfl_xor(sv, 1);
        sv += __shfl_xor(sv, 2);
        sv += __shfl_xor(sv, 4);
        sv += __shfl_xor(sv, 8);
        if (lr == 0)
          ps[(int64_t)(mbase + r) * 64 + ntile * 4 + wn] = sv;
      }
    }
  } else {
#pragma unroll
    for (int mf = 0; mf < MF; ++mf)
#pragma unroll
      for (int nf = 0; nf < 4; ++nf) {
        f32x4 v = acc[mf][nf];
        int m = m0 + wm * (MF * 16) + mf * 16 + lc * 4;
        int n = n0 + wn * 64 + nf * 16 + lr;
        U16x4 pk{f2bf(v[0]), f2bf(v[1]), f2bf(v[2]), f2bf(v[3])};
        *(U16x4*)(otr + trBatch * b + (int64_t)n * trStride + m) = pk;
      }
  }
}

// ---------------------------------------------------------------------------
// scores GEMM (128x128, split-K): scores'[c][d] = sum_l e_q[c,l]*e_k[d,l]
// ---------------------------------------------------------------------------
__global__ __launch_bounds__(256) void gemm_scores(
    const u16* __restrict__ A, const u16* __restrict__ B,
    float* __restrict__ orm,
    int sA, int64_t aBatch, int sB, int64_t bBatch,
    int rmStride, int64_t rmBatch,
    int nsplit, int kStep, int64_t splitOut)
{
  __shared__ __align__(16) u16 As[128 * 32];
  __shared__ __align__(16) u16 Bs[128 * 32];

  const int tid = threadIdx.x;
  int b = blockIdx.z, split = 0;
  if (nsplit > 1) { split = b % nsplit; b /= nsplit; }
  const int m0  = blockIdx.y * 128;
  const int n0  = blockIdx.x * 128;
  const int lane = tid & 63, wave = tid >> 6;
  const int wm = wave >> 1, wn = wave & 1;
  const int lr = lane & 15, lc = lane >> 4;

  f32x4 acc[4][4];
#pragma unroll
  for (int i = 0; i < 4; ++i)
#pragma unroll
    for (int j = 0; j < 4; ++j) acc[i][j] = f32x4{0.f, 0.f, 0.f, 0.f};

  const u16* Ab = A + (int64_t)b * aBatch + split * kStep;
  const u16* Bb = B + (int64_t)b * bBatch + split * kStep;

  const int srow = tid >> 2;
  const int sc   = tid & 3;
  const int scs  = sc ^ (srow & 3);

  for (int kc = 0; kc < 512; kc += 32) {
#pragma unroll
    for (int it = 0; it < 2; ++it) {
      int row = srow + it * 64;
      GLOAD16(Ab + (int64_t)(m0 + row) * sA + kc + scs * 8,
              &As[wave * 512 + it * 2048]);
      GLOAD16(Bb + (int64_t)(n0 + row) * sB + kc + scs * 8,
              &Bs[wave * 512 + it * 2048]);
    }
    __syncthreads();

    bf16x8 af[4], bfr[4];
#pragma unroll
    for (int mf = 0; mf < 4; ++mf) {
      int row = wm * 64 + mf * 16 + lr;
      af[mf] = *(const bf16x8*)&As[row * 32 + ((lc ^ (row & 3)) * 8)];
    }
#pragma unroll
    for (int nf = 0; nf < 4; ++nf) {
      int row = wn * 64 + nf * 16 + lr;
      bfr[nf] = *(const bf16x8*)&Bs[row * 32 + ((lc ^ (row & 3)) * 8)];
    }
#pragma unroll
    for (int mf = 0; mf < 4; ++mf)
#pragma unroll
      for (int nf = 0; nf < 4; ++nf)
        acc[mf][nf] = __builtin_amdgcn_mfma_f32_16x16x32_bf16(af[mf], bfr[nf], acc[mf][nf], 0, 0, 0);
    __syncthreads();
  }

#pragma unroll
  for (int mf = 0; mf < 4; ++mf)
#pragma unroll
    for (int nf = 0; nf < 4; ++nf) {
      f32x4 v = acc[mf][nf];
      int m = m0 + wm * 64 + mf * 16 + lc * 4;
      int n = n0 + wn * 64 + nf * 16 + lr;
      float* p = orm + splitOut * split + rmBatch * b + (int64_t)m * rmStride + n;
#pragma unroll
      for (int r = 0; r < 4; ++r) p[(int64_t)r * rmStride] = v[r];
    }
}

// ===========================================================================
// k_tail: fused y = mattn@v -> gate = Wg@[y;x], res = Wr@x, sigmoid blend.
// ===========================================================================
__global__ __launch_bounds__(512) void k_tail(
    const u16* __restrict__ mattn, const u16* __restrict__ qkvT,
    const u16* __restrict__ ycatT, const u16* __restrict__ Wg,
    const u16* __restrict__ Wr, float* __restrict__ out)
{
  __shared__ __align__(16) u16 As[256 * 32];    // 16 KB (mattn / Wg slices)
  __shared__ __align__(16) u16 As2[256 * 32];   // 16 KB (Wr slices)
  __shared__ __align__(16) u16 Bs[128 * 32];    // 8 KB  (v / x slices)
  __shared__ __align__(16) u16 yT[128 * 260];   // 65 KB (y^T, padded)

  const int b = blockIdx.y, l0 = blockIdx.x * 128;
  const int tid = threadIdx.x;
  const int lane = tid & 63, wave = tid >> 6;
  const int wm = wave >> 1, wn = wave & 1;
  const int lr = lane & 15, lc = lane >> 4;

  const int srow = tid >> 2, sc = tid & 3;
  const int scs = sc ^ (srow & 3);

  f32x4 acc[4][4];
#pragma unroll
  for (int i = 0; i < 4; ++i)
#pragma unroll
    for (int j = 0; j < 4; ++j) acc[i][j] = f32x4{0.f, 0.f, 0.f, 0.f};

  // ---- phase 1: y[256][128] = mattn @ v ----
  const u16* Am = mattn + (int64_t)b * 65536;
  const u16* Vv = qkvT + (int64_t)b * 4096 * 768 + 512;
  for (int kc = 0; kc < 256; kc += 32) {
#pragma unroll
    for (int it = 0; it < 2; ++it) {
      int row = srow + it * 128;
      GLOAD16(Am + (int64_t)row * 256 + kc + scs * 8,
              &As[wave * 512 + it * 4096]);
    }
    GLOAD16(Vv + (int64_t)(l0 + srow) * 768 + kc + scs * 8, &Bs[wave * 512]);
    __syncthreads();

    bf16x8 af[4], bfr[4];
#pragma unroll
    for (int mf = 0; mf < 4; ++mf) {
      int row = wm * 64 + mf * 16 + lr;
      af[mf] = *(const bf16x8*)&As[row * 32 + ((lc ^ (row & 3)) * 8)];
    }
#pragma unroll
    for (int nf = 0; nf < 4; ++nf) {
      int row = wn * 64 + nf * 16 + lr;
      bfr[nf] = *(const bf16x8*)&Bs[row * 32 + ((lc ^ (row & 3)) * 8)];
    }
#pragma unroll
    for (int mf = 0; mf < 4; ++mf)
#pragma unroll
      for (int nf = 0; nf < 4; ++nf)
        acc[mf][nf] = __builtin_amdgcn_mfma_f32_16x16x32_bf16(af[mf], bfr[nf], acc[mf][nf], 0, 0, 0);
    __syncthreads();
  }

  // transpose y into LDS: yT[l_local][ch] bf16 (padded stride 260)
#pragma unroll
  for (int mf = 0; mf < 4; ++mf)
#pragma unroll
    for (int nf = 0; nf < 4; ++nf) {
      f32x4 v = acc[mf][nf];
      int m = wm * 64 + mf * 16 + lc * 4;
      int n = wn * 64 + nf * 16 + lr;
      U16x4 pk{f2bf(v[0]), f2bf(v[1]), f2bf(v[2]), f2bf(v[3])};
      *(U16x4*)&yT[n * 260 + m] = pk;
    }
  __syncthreads();

  // ---- phase 2: gate (K=512) + res (K 256..511), dual accumulators ----
  f32x4 acc2[4][4];
#pragma unroll
  for (int i = 0; i < 4; ++i)
#pragma unroll
    for (int j = 0; j < 4; ++j) {
      acc[i][j] = f32x4{0.f, 0.f, 0.f, 0.f};
      acc2[i][j] = f32x4{0.f, 0.f, 0.f, 0.f};
    }

  const u16* Xc = ycatT + (int64_t)b * 4096 * 512;
  for (int kc = 0; kc < 512; kc += 32) {
    const bool xk = (kc >= 256);
#pragma unroll
    for (int it = 0; it < 2; ++it) {
      int row = srow + it * 128;
      GLOAD16(Wg + (int64_t)row * 512 + kc + scs * 8,
              &As[wave * 512 + it * 4096]);
    }
    if (xk) {
#pragma unroll
      for (int it = 0; it < 2; ++it) {
        int row = srow + it * 128;
        GLOAD16(Wr + (int64_t)row * 256 + (kc - 256) + scs * 8,
                &As2[wave * 512 + it * 4096]);
      }
      GLOAD16(Xc + (int64_t)(l0 + srow) * 512 + kc + scs * 8, &Bs[wave * 512]);
    }
    __syncthreads();

    bf16x8 af[4], bfr[4];
#pragma unroll
    for (int nf = 0; nf < 4; ++nf) {
      int row = wn * 64 + nf * 16 + lr;
      if (xk) bfr[nf] = *(const bf16x8*)&Bs[row * 32 + ((lc ^ (row & 3)) * 8)];
      else    bfr[nf] = *(const bf16x8*)&yT[row * 260 + kc + lc * 8];
    }
#pragma unroll
    for (int mf = 0; mf < 4; ++mf) {
      int row = wm * 64 + mf * 16 + lr;
      af[mf] = *(const bf16x8*)&As[row * 32 + ((lc ^ (row & 3)) * 8)];
    }
#pragma unroll
    for (int mf = 0; mf < 4; ++mf)
#pragma unroll
      for (int nf = 0; nf < 4; ++nf)
        acc[mf][nf] = __builtin_amdgcn_mfma_f32_16x16x32_bf16(af[mf], bfr[nf], acc[mf][nf], 0, 0, 0);
    if (xk) {
      bf16x8 af2[4];
#pragma unroll
      for (int mf = 0; mf < 4; ++mf) {
        int row = wm * 64 + mf * 16 + lr;
        af2[mf] = *(const bf16x8*)&As2[row * 32 + ((lc ^ (row & 3)) * 8)];
      }
#pragma unroll
      for (int mf = 0; mf < 4; ++mf)
#pragma unroll
        for (int nf = 0; nf < 4; ++nf)
          acc2[mf][nf] = __builtin_amdgcn_mfma_f32_16x16x32_bf16(af2[mf], bfr[nf], acc2[mf][nf], 0, 0, 0);
    }
    __syncthreads();
  }

  // epilogue: out = sig(gpre)*res + (1-sig)*y
#pragma unroll
  for (int mf = 0; mf < 4; ++mf)
#pragma unroll
    for (int nf = 0; nf < 4; ++nf) {
      f32x4 g4 = acc[mf][nf], r4 = acc2[mf][nf];
      int m = wm * 64 + mf * 16 + lc * 4;
      int n = wn * 64 + nf * 16 + lr;
      U16x4 yv = *(const U16x4*)&yT[n * 260 + m];
      const u16* yp = (const u16*)&yv;
      float* p = out + (int64_t)b * 256 * 4096 + (int64_t)m * 4096 + l0 + n;
#pragma unroll
      for (int r = 0; r < 4; ++r) {
        float g = 1.f / (1.f + __expf(-g4[r]));
        p[(int64_t)r * 4096] = g * r4[r] + (1.f - g) * bf2f(yp[r]);
      }
    }
}

// ---------------------------------------------------------------------------
// merged prep: all weight converts + zero page in ONE kernel
// ---------------------------------------------------------------------------
__global__ void k_prep(const float* __restrict__ wqkv, const float* __restrict__ wmod,
                       const float* __restrict__ wgate, const float* __restrict__ wres,
                       u16* __restrict__ Wa, u16* __restrict__ Wb,
                       u16* __restrict__ Wg, u16* __restrict__ Wr,
                       uint32_t* __restrict__ zpage) {
  int bid = blockIdx.x, t = threadIdx.x;
  if (bid < 6912) {                           // Wa: 768 x (9*256)
    int idx = bid * 256 + t;
    if (idx < 768 * 2304) {
      int oc = idx / 2304, r = idx % 2304;
      int tap = r >> 8, ic = r & 255;
      Wa[idx] = f2bf(wqkv[((oc * 256 + ic) * 3 + tap / 3) * 3 + tap % 3]);
    }
  } else if (bid < 8448) {                    // Wb: 512 x (3*256)
    int idx = (bid - 6912) * 256 + t;
    if (idx < 512 * 768) {
      int oc = idx / 768, r = idx % 768;
      int tap = r >> 8, ic = r & 255;
      Wb[idx] = f2bf(wmod[(oc * 256 + ic) * 3 + tap]);
    }
  } else if (bid < 8960) {                    // Wg: 256 x 512
    int idx = (bid - 8448) * 256 + t;
    if (idx < 131072) Wg[idx] = f2bf(wgate[idx]);
  } else if (bid < 9216) {                    // Wr: 256 x 256
    int idx = (bid - 8960) * 256 + t;
    if (idx < 65536) Wr[idx] = f2bf(wres[idx]);
  } else {
    if (t < 64) zpage[t] = 0u;
  }
}

// ---------------------------------------------------------------------------
// x (B,256,4096) f32 -> ycatT[b][l][256+c] bf16 (x part of concat buffer)
// ---------------------------------------------------------------------------
__global__ __launch_bounds__(256) void k_xT(const float* __restrict__ x, u16* __restrict__ ycat) {
  __shared__ float tile[64 * 68];
  int b = blockIdx.z, c0 = blockIdx.y * 64, l0 = blockIdx.x * 64;
  int t = threadIdx.x;
  int cc = t >> 2, part = t & 3;
  const float* xp = x + ((int64_t)(b * 256 + c0 + cc)) * 4096 + l0 + part * 16;
#pragma unroll
  for (int j = 0; j < 4; ++j) {
    F4 v = *(const F4*)(xp + j * 4);
    float* tp = &tile[cc * 68 + part * 16 + j * 4];
    tp[0] = v.x; tp[1] = v.y; tp[2] = v.z; tp[3] = v.w;
  }
  __syncthreads();
  int l = t >> 2;
  u16* op = ycat + ((int64_t)b * 4096 + l0 + l) * 512 + 256 + c0 + part * 16;
  __align__(16) u16 tmp[16];
#pragma unroll
  for (int j = 0; j < 16; ++j) tmp[j] = f2bf(tile[(part * 16 + j) * 68 + l]);
  *(V16*)(op) = *(V16*)&tmp[0];
  *(V16*)(op + 8) = *(V16*)&tmp[8];
}

// sum 64 partials per channel -> 1/S
__global__ void k_statsB64(const float* __restrict__ part, float* __restrict__ inv) {
  int idx = blockIdx.x * 256 + threadIdx.x;   // 4096 channels (b*512+m)
  float S = 0.f;
#pragma unroll
  for (int s = 0; s < 64; ++s) S += part[(int64_t)idx * 64 + s];
  inv[idx] = 1.0f / S;
}

// softmax over d of (sum split-K partials)*invSq[c]*invSk[d]*(1/16)
__global__ __launch_bounds__(256) void k_softmax_attn(
    const float* __restrict__ sc, const float* __restrict__ invS,
    u16* __restrict__ ma, int nsplit, int64_t splitOff) {
  int c = blockIdx.x, b = blockIdx.y;
  int64_t base = ((int64_t)b * 256 + c) * 256;
  int t = threadIdx.x;
  float z = 0.f;
  for (int s = 0; s < nsplit; ++s) z += sc[(int64_t)s * splitOff + base + t];
  float iq = invS[(int64_t)b * 512 + c];
  float ik = invS[(int64_t)b * 512 + 256 + t];
  z *= iq * ik * 0.0625f;
  __shared__ float red[256];
  red[t] = z; __syncthreads();
  for (int s = 128; s > 0; s >>= 1) { if (t < s) red[t] = fmaxf(red[t], red[t + s]); __syncthreads(); }
  float M = red[0]; __syncthreads();
  float p = __expf(z - M);
  red[t] = p; __syncthreads();
  for (int s = 128; s > 0; s >>= 1) { if (t < s) red[t] += red[t + s]; __syncthreads(); }
  ma[base + t] = f2bf(p / red[0]);
}

// ---------------------------------------------------------------------------
extern "C" void kernel_launch(void* const* d_in, const int* in_sizes, int n_in,
                              void* d_out, int out_size, void* d_ws, size_t ws_size,
                              hipStream_t stream) {
  (void)in_sizes; (void)n_in; (void)out_size; (void)ws_size;
  const float* x      = (const float*)d_in[0];
  const float* w_qkv  = (const float*)d_in[1];
  const float* w_mod  = (const float*)d_in[2];
  const float* w_res  = (const float*)d_in[3];
  const float* w_gate = (const float*)d_in[4];
  float* out = (float*)d_out;

  char* p = (char*)d_ws;
  auto take = [&](size_t n) { void* r = (void*)p; p += (n + 255) & ~(size_t)255; return r; };
  u16*    zpage  = (u16*)take(256);        // zero page for masked conv taps
  u16*    qkvT   = (u16*)take(50331648);   // [b][l][768] bf16 (q|k|v)
  u16*    ycatT  = (u16*)take(33554432);   // [b][l][512] bf16 (x in cols 256+)
  u16*    eT     = (u16*)take(33554432);   // [b][512ch][l] bf16 (e_q|e_k)
  float*  scores = (float*)take(16777216); // [8 splits][b][c][d] f32
  u16*    mattn  = (u16*)take(1048576);    // [b][c][d] bf16
  float*  partS  = (float*)take(1048576);  // [b*512+ch][64] partial sums
  float*  invS   = (float*)take(16384);    // [b*512+ch] 1/S
  u16*    Wa     = (u16*)take(3538944);    // 768 x 2304
  u16*    Wb     = (u16*)take(786432);     // 512 x 768
  u16*    Wg     = (u16*)take(262144);     // 256 x 512
  u16*    Wr     = (u16*)take(131072);     // 256 x 256

  k_prep<<<9217, 256, 0, stream>>>(w_qkv, w_mod, w_gate, w_res,
                                   Wa, Wb, Wg, Wr, (uint32_t*)zpage);
  k_xT<<<dim3(64, 4, 8), 256, 0, stream>>>(x, ycatT);

  // qkv = conv2d(x, w_qkv): M=768 N=4096 K=9*256 -> qkvT bf16
  // 4-wave blocks, 2 blocks/CU (80 KiB LDS), 1024 blocks = 2 exact rounds
  gemm2b_bf16<2><<<1024, 256, 0, stream>>>(
      Wa, ycatT + 256, qkvT,
      2304, 512, (int64_t)4096 * 512,
      768, (int64_t)4096 * 768, 4, zpage);

  // mod = conv1d(v, w_mod) FUSED with e = exp(-relu(q*mod)) -> eT + partS
  gemmOv_bf16<1, 8, 1><<<256, 512, 0, stream>>>(
      Wb, qkvT + 512, nullptr,
      768, 768, (int64_t)4096 * 768,
      0, 0, 2, zpage,
      qkvT, eT, partS);

  k_statsB64<<<16, 256, 0, stream>>>(partS, invS);

  // scores'[c][d] = sum_l e_q[c,l]*e_k[d,l]: M=256 N=256 K=4096, split-K x8
  gemm_scores<<<dim3(2, 2, 64), 256, 0, stream>>>(
      eT, eT + (int64_t)256 * 4096, scores,
      4096, (int64_t)512 * 4096,
      4096, (int64_t)512 * 4096,
      256, (int64_t)256 * 256,
      8, 512, (int64_t)8 * 256 * 256);

  k_softmax_attn<<<dim3(256, 8), 256, 0, stream>>>(
      scores, invS, mattn, 8, (int64_t)8 * 256 * 256);

  // fused tail: y = mattn@v -> gate/res/blend -> out
  k_tail<<<dim3(32, 8), 512, 0, stream>>>(mattn, qkvT, ycatT, Wg, Wr, out);
}

// Round 19
// 218.206 us; speedup vs baseline: 1.0260x; 1.0260x over previous
//
#include <hip/hip_runtime.h>
#include <cstdint>

typedef unsigned short u16;
using bf16x8 = __attribute__((ext_vector_type(8))) short;   // 8 bf16 = 4 VGPR
using f32x4  = __attribute__((ext_vector_type(4))) float;   // MFMA acc

struct alignas(16) V16 { uint32_t a, b, c, d; };            // 16B chunk
struct alignas(8)  U16x4 { u16 a, b, c, d; };
struct alignas(16) F4 { float x, y, z, w; };

__device__ __forceinline__ u16 f2bf(float f) {              // RNE f32->bf16
  uint32_t u = __float_as_uint(f);
  u += 0x7fffu + ((u >> 16) & 1u);
  return (u16)(u >> 16);
}
__device__ __forceinline__ float bf2f(u16 h) {
  return __uint_as_float(((uint32_t)h) << 16);
}

// async global->LDS, 16B per lane; dest = wave-uniform base + lane*16 (linear)
#define GLOAD16(g, l) __builtin_amdgcn_global_load_lds(                         \
    (const __attribute__((address_space(1))) uint32_t*)(g),                     \
    (__attribute__((address_space(3))) uint32_t*)(l), 16, 0, 0)

// ===========================================================================
// Overlap-pipelined conv-GEMM (r16 champion): BM = MF*32, BN=256, BK=64
// slab, 8 waves 2M x 4N, per-wave (MF*16)x64, acc[MF][4].
// Fence-free interleave (compiler counted-lgkmcnt overlap) + T5 setprio.
// LDS ring-2 dbuf; boundary = vmcnt(0)+barrier per slab.
// Swizzle: 128-B rows, chunk ^= (row&7) (verified 0-conflict), applied on
// global SOURCE + ds_read side; gload_lds dest linear (rule #21).
// FUSE=1 (conv1d): epilogue e = exp(-relu(q*mod)) -> eT + partial sums.
// Plateau evidence: counted-vmcnt ring-3 (r10,r17), 2 blocks/CU (r18),
// 16-wave (r8), 8-phase lockstep (r5), fine-phase (r6) all null/worse.
// ===========================================================================
template<int MODE, int MF, int FUSE = 0>
__global__ __launch_bounds__(512, 2) void gemmOv_bf16(
    const u16* __restrict__ A, const u16* __restrict__ B, u16* __restrict__ otr,
    int sA, int sB, int64_t bBatch, int trStride, int64_t trBatch, int MT,
    const u16* __restrict__ zpage,
    const u16* __restrict__ fq = nullptr, u16* __restrict__ eOut = nullptr,
    float* __restrict__ partS = nullptr)
{
  constexpr int NS = (MODE == 2) ? 36 : 12;    // BK=64 slabs: NTAPS*(256/64)
  constexpr int ASL = MF * 2048;               // A slab u16 (BM*64)
  constexpr int SLAB = ASL + 16384;            // + B slab (256*64)
  __shared__ __align__(16) u16 lds[2 * SLAB];

  const int tid = threadIdx.x;
  const int q = gridDim.x >> 3;                // XCD-aware bijective swizzle
  const int flat = (blockIdx.x & 7) * q + (blockIdx.x >> 3);
  const int per_b = MT * 16;                   // 16 n-tiles of 256
  const int b = flat / per_b, rem = flat % per_b;
  const int ntile = rem / MT, mtile = rem % MT;
  const int m0 = mtile * (MF * 32), n0 = ntile * 256;
  const u16* Bb = B + (int64_t)b * bBatch;

  const int lane = tid & 63, wave = tid >> 6;
  const int wm = wave >> 2, wn = wave & 3;     // 2M x 4N waves
  const int lr = lane & 15, lc = lane >> 4;

  const int lrow8 = lane >> 3;
  const int sch  = lane & 7;
  const int scs  = sch ^ (lrow8 & 7);
  const u16* aSrc[MF / 2];
  const u16* bSrc[4];
  int bRow[4];
#pragma unroll
  for (int j = 0; j < MF / 2; ++j)
    aSrc[j] = A + (int64_t)(m0 + wave * (MF * 4) + j * 8 + lrow8) * sA + scs * 8;
#pragma unroll
  for (int j = 0; j < 4; ++j) {
    bRow[j] = n0 + wave * 32 + j * 8 + lrow8;
    bSrc[j] = Bb + (int64_t)bRow[j] * sB + scs * 8;
  }

  auto stageA = [&](int s) {                   // MF/2 loads/thread
    const int kOff = (s >> 2) * 256 + ((s & 3) << 6);
    u16* dst = lds + (s & 1) * SLAB + wave * (MF / 2) * 512;
#pragma unroll
    for (int j = 0; j < MF / 2; ++j)
      GLOAD16(aSrc[j] + kOff, dst + j * 512);
  };
  auto stageB = [&](int s) {                   // 4 loads/thread (tap-masked)
    const int tap = s >> 2, kc = (s & 3) << 6;
    int off, dh = 0, dw = 0;
    if constexpr (MODE == 2) { dh = tap / 3 - 1; dw = tap % 3 - 1; off = dh * 64 + dw; }
    else                     { off = tap - 1; }
    u16* dst = lds + (s & 1) * SLAB + ASL + wave * 2048;
#pragma unroll
    for (int j = 0; j < 4; ++j) {
      bool ok;
      if constexpr (MODE == 2) {
        int hh = (bRow[j] >> 6) + dh, ww = (bRow[j] & 63) + dw;
        ok = ((unsigned)hh < 64u) && ((unsigned)ww < 64u);
      } else {
        ok = ((unsigned)(bRow[j] + off) < 4096u);
      }
      const u16* src = ok ? (bSrc[j] + (int64_t)off * sB + kc) : zpage;
      GLOAD16(src, dst + j * 512);
    }
  };

  f32x4 acc[MF][4];
#pragma unroll
  for (int i = 0; i < MF; ++i)
#pragma unroll
    for (int j = 0; j < 4; ++j) acc[i][j] = f32x4{0.f, 0.f, 0.f, 0.f};

  stageA(0); stageB(0);
  asm volatile("s_waitcnt vmcnt(0)" ::: "memory");
  __builtin_amdgcn_s_barrier();
  __builtin_amdgcn_sched_barrier(0);

  for (int s = 0; s < NS; ++s) {
    const u16* As = lds + (s & 1) * SLAB;
    const u16* Bs = As + ASL;
    const bool pf = (s + 1 < NS);
    bf16x8 bfr[4], af[MF];

    // ---- k-half 0: reads + stage A(s+1) + MFMA cluster (T5) ----
#pragma unroll
    for (int nf = 0; nf < 4; ++nf) {
      int row = wn * 64 + nf * 16 + lr;
      bfr[nf] = *(const bf16x8*)&Bs[row * 64 + ((lc ^ (row & 7)) * 8)];
    }
#pragma unroll
    for (int mf = 0; mf < MF; ++mf) {
      int row = wm * (MF * 16) + mf * 16 + lr;
      af[mf] = *(const bf16x8*)&As[row * 64 + ((lc ^ (row & 7)) * 8)];
    }
    if (pf) stageA(s + 1);
    __builtin_amdgcn_s_setprio(1);
#pragma unroll
    for (int mf = 0; mf < MF; ++mf)
#pragma unroll
      for (int nf = 0; nf < 4; ++nf)
        acc[mf][nf] = __builtin_amdgcn_mfma_f32_16x16x32_bf16(af[mf], bfr[nf], acc[mf][nf], 0, 0, 0);
    __builtin_amdgcn_s_setprio(0);

    // ---- k-half 1: reads + stage B(s+1) + MFMA cluster (T5) ----
#pragma unroll
    for (int nf = 0; nf < 4; ++nf) {
      int row = wn * 64 + nf * 16 + lr;
      bfr[nf] = *(const bf16x8*)&Bs[row * 64 + (((4 + lc) ^ (row & 7)) * 8)];
    }
#pragma unroll
    for (int mf = 0; mf < MF; ++mf) {
      int row = wm * (MF * 16) + mf * 16 + lr;
      af[mf] = *(const bf16x8*)&As[row * 64 + (((4 + lc) ^ (row & 7)) * 8)];
    }
    if (pf) stageB(s + 1);
    __builtin_amdgcn_s_setprio(1);
#pragma unroll
    for (int mf = 0; mf < MF; ++mf)
#pragma unroll
      for (int nf = 0; nf < 4; ++nf)
        acc[mf][nf] = __builtin_amdgcn_mfma_f32_16x16x32_bf16(af[mf], bfr[nf], acc[mf][nf], 0, 0, 0);
    __builtin_amdgcn_s_setprio(0);

    if (pf) {
      asm volatile("s_waitcnt vmcnt(0)" ::: "memory");
      __builtin_amdgcn_s_barrier();
      __builtin_amdgcn_sched_barrier(0);
    }
  }

  if constexpr (FUSE) {
    const u16* qk = fq + (int64_t)b * 4096 * 768;
    u16* eb = eOut + (int64_t)b * 512 * 4096;
    float* ps = partS + (int64_t)b * 512 * 64;
#pragma unroll
    for (int mf = 0; mf < MF; ++mf) {
      const int mbase = m0 + wm * (MF * 16) + mf * 16 + lc * 4;
      float sp[4] = {0.f, 0.f, 0.f, 0.f};
#pragma unroll
      for (int nf = 0; nf < 4; ++nf) {
        int n = n0 + wn * 64 + nf * 16 + lr;
        U16x4 qv = *(const U16x4*)(qk + (int64_t)n * 768 + mbase);
        const u16* qp = (const u16*)&qv;
        f32x4 v = acc[mf][nf];
#pragma unroll
        for (int r = 0; r < 4; ++r) {
          float z = bf2f(qp[r]) * v[r];
          float e = __expf(z > 0.f ? -z : 0.f);
          sp[r] += e;
          eb[(int64_t)(mbase + r) * 4096 + n] = f2bf(e);
        }
      }
#pragma unroll
      for (int r = 0; r < 4; ++r) {
        float sv = sp[r];
        sv += __shfl_xor(sv, 1);
        sv += __shfl_xor(sv, 2);
        sv += __shfl_xor(sv, 4);
        sv += __shfl_xor(sv, 8);
        if (lr == 0)
          ps[(int64_t)(mbase + r) * 64 + ntile * 4 + wn] = sv;
      }
    }
  } else {
#pragma unroll
    for (int mf = 0; mf < MF; ++mf)
#pragma unroll
      for (int nf = 0; nf < 4; ++nf) {
        f32x4 v = acc[mf][nf];
        int m = m0 + wm * (MF * 16) + mf * 16 + lc * 4;
        int n = n0 + wn * 64 + nf * 16 + lr;
        U16x4 pk{f2bf(v[0]), f2bf(v[1]), f2bf(v[2]), f2bf(v[3])};
        *(U16x4*)(otr + trBatch * b + (int64_t)n * trStride + m) = pk;
      }
  }
}

// ---------------------------------------------------------------------------
// scores GEMM (128x128, split-K): scores'[c][d] = sum_l e_q[c,l]*e_k[d,l]
// ---------------------------------------------------------------------------
__global__ __launch_bounds__(256) void gemm_scores(
    const u16* __restrict__ A, const u16* __restrict__ B,
    float* __restrict__ orm,
    int sA, int64_t aBatch, int sB, int64_t bBatch,
    int rmStride, int64_t rmBatch,
    int nsplit, int kStep, int64_t splitOut)
{
  __shared__ __align__(16) u16 As[128 * 32];
  __shared__ __align__(16) u16 Bs[128 * 32];

  const int tid = threadIdx.x;
  int b = blockIdx.z, split = 0;
  if (nsplit > 1) { split = b % nsplit; b /= nsplit; }
  const int m0  = blockIdx.y * 128;
  const int n0  = blockIdx.x * 128;
  const int lane = tid & 63, wave = tid >> 6;
  const int wm = wave >> 1, wn = wave & 1;
  const int lr = lane & 15, lc = lane >> 4;

  f32x4 acc[4][4];
#pragma unroll
  for (int i = 0; i < 4; ++i)
#pragma unroll
    for (int j = 0; j < 4; ++j) acc[i][j] = f32x4{0.f, 0.f, 0.f, 0.f};

  const u16* Ab = A + (int64_t)b * aBatch + split * kStep;
  const u16* Bb = B + (int64_t)b * bBatch + split * kStep;

  const int srow = tid >> 2;
  const int sc   = tid & 3;
  const int scs  = sc ^ (srow & 3);

  for (int kc = 0; kc < 512; kc += 32) {
#pragma unroll
    for (int it = 0; it < 2; ++it) {
      int row = srow + it * 64;
      GLOAD16(Ab + (int64_t)(m0 + row) * sA + kc + scs * 8,
              &As[wave * 512 + it * 2048]);
      GLOAD16(Bb + (int64_t)(n0 + row) * sB + kc + scs * 8,
              &Bs[wave * 512 + it * 2048]);
    }
    __syncthreads();

    bf16x8 af[4], bfr[4];
#pragma unroll
    for (int mf = 0; mf < 4; ++mf) {
      int row = wm * 64 + mf * 16 + lr;
      af[mf] = *(const bf16x8*)&As[row * 32 + ((lc ^ (row & 3)) * 8)];
    }
#pragma unroll
    for (int nf = 0; nf < 4; ++nf) {
      int row = wn * 64 + nf * 16 + lr;
      bfr[nf] = *(const bf16x8*)&Bs[row * 32 + ((lc ^ (row & 3)) * 8)];
    }
#pragma unroll
    for (int mf = 0; mf < 4; ++mf)
#pragma unroll
      for (int nf = 0; nf < 4; ++nf)
        acc[mf][nf] = __builtin_amdgcn_mfma_f32_16x16x32_bf16(af[mf], bfr[nf], acc[mf][nf], 0, 0, 0);
    __syncthreads();
  }

#pragma unroll
  for (int mf = 0; mf < 4; ++mf)
#pragma unroll
    for (int nf = 0; nf < 4; ++nf) {
      f32x4 v = acc[mf][nf];
      int m = m0 + wm * 64 + mf * 16 + lc * 4;
      int n = n0 + wn * 64 + nf * 16 + lr;
      float* p = orm + splitOut * split + rmBatch * b + (int64_t)m * rmStride + n;
#pragma unroll
      for (int r = 0; r < 4; ++r) p[(int64_t)r * rmStride] = v[r];
    }
}

// ===========================================================================
// k_tail: fused y = mattn@v -> gate = Wg@[y;x], res = Wr@x, sigmoid blend.
// ===========================================================================
__global__ __launch_bounds__(512) void k_tail(
    const u16* __restrict__ mattn, const u16* __restrict__ qkvT,
    const u16* __restrict__ ycatT, const u16* __restrict__ Wg,
    const u16* __restrict__ Wr, float* __restrict__ out)
{
  __shared__ __align__(16) u16 As[256 * 32];    // 16 KB (mattn / Wg slices)
  __shared__ __align__(16) u16 As2[256 * 32];   // 16 KB (Wr slices)
  __shared__ __align__(16) u16 Bs[128 * 32];    // 8 KB  (v / x slices)
  __shared__ __align__(16) u16 yT[128 * 260];   // 65 KB (y^T, padded)

  const int b = blockIdx.y, l0 = blockIdx.x * 128;
  const int tid = threadIdx.x;
  const int lane = tid & 63, wave = tid >> 6;
  const int wm = wave >> 1, wn = wave & 1;
  const int lr = lane & 15, lc = lane >> 4;

  const int srow = tid >> 2, sc = tid & 3;
  const int scs = sc ^ (srow & 3);

  f32x4 acc[4][4];
#pragma unroll
  for (int i = 0; i < 4; ++i)
#pragma unroll
    for (int j = 0; j < 4; ++j) acc[i][j] = f32x4{0.f, 0.f, 0.f, 0.f};

  // ---- phase 1: y[256][128] = mattn @ v ----
  const u16* Am = mattn + (int64_t)b * 65536;
  const u16* Vv = qkvT + (int64_t)b * 4096 * 768 + 512;
  for (int kc = 0; kc < 256; kc += 32) {
#pragma unroll
    for (int it = 0; it < 2; ++it) {
      int row = srow + it * 128;
      GLOAD16(Am + (int64_t)row * 256 + kc + scs * 8,
              &As[wave * 512 + it * 4096]);
    }
    GLOAD16(Vv + (int64_t)(l0 + srow) * 768 + kc + scs * 8, &Bs[wave * 512]);
    __syncthreads();

    bf16x8 af[4], bfr[4];
#pragma unroll
    for (int mf = 0; mf < 4; ++mf) {
      int row = wm * 64 + mf * 16 + lr;
      af[mf] = *(const bf16x8*)&As[row * 32 + ((lc ^ (row & 3)) * 8)];
    }
#pragma unroll
    for (int nf = 0; nf < 4; ++nf) {
      int row = wn * 64 + nf * 16 + lr;
      bfr[nf] = *(const bf16x8*)&Bs[row * 32 + ((lc ^ (row & 3)) * 8)];
    }
#pragma unroll
    for (int mf = 0; mf < 4; ++mf)
#pragma unroll
      for (int nf = 0; nf < 4; ++nf)
        acc[mf][nf] = __builtin_amdgcn_mfma_f32_16x16x32_bf16(af[mf], bfr[nf], acc[mf][nf], 0, 0, 0);
    __syncthreads();
  }

  // transpose y into LDS: yT[l_local][ch] bf16 (padded stride 260)
#pragma unroll
  for (int mf = 0; mf < 4; ++mf)
#pragma unroll
    for (int nf = 0; nf < 4; ++nf) {
      f32x4 v = acc[mf][nf];
      int m = wm * 64 + mf * 16 + lc * 4;
      int n = wn * 64 + nf * 16 + lr;
      U16x4 pk{f2bf(v[0]), f2bf(v[1]), f2bf(v[2]), f2bf(v[3])};
      *(U16x4*)&yT[n * 260 + m] = pk;
    }
  __syncthreads();

  // ---- phase 2: gate (K=512) + res (K 256..511), dual accumulators ----
  f32x4 acc2[4][4];
#pragma unroll
  for (int i = 0; i < 4; ++i)
#pragma unroll
    for (int j = 0; j < 4; ++j) {
      acc[i][j] = f32x4{0.f, 0.f, 0.f, 0.f};
      acc2[i][j] = f32x4{0.f, 0.f, 0.f, 0.f};
    }

  const u16* Xc = ycatT + (int64_t)b * 4096 * 512;
  for (int kc = 0; kc < 512; kc += 32) {
    const bool xk = (kc >= 256);
#pragma unroll
    for (int it = 0; it < 2; ++it) {
      int row = srow + it * 128;
      GLOAD16(Wg + (int64_t)row * 512 + kc + scs * 8,
              &As[wave * 512 + it * 4096]);
    }
    if (xk) {
#pragma unroll
      for (int it = 0; it < 2; ++it) {
        int row = srow + it * 128;
        GLOAD16(Wr + (int64_t)row * 256 + (kc - 256) + scs * 8,
                &As2[wave * 512 + it * 4096]);
      }
      GLOAD16(Xc + (int64_t)(l0 + srow) * 512 + kc + scs * 8, &Bs[wave * 512]);
    }
    __syncthreads();

    bf16x8 af[4], bfr[4];
#pragma unroll
    for (int nf = 0; nf < 4; ++nf) {
      int row = wn * 64 + nf * 16 + lr;
      if (xk) bfr[nf] = *(const bf16x8*)&Bs[row * 32 + ((lc ^ (row & 3)) * 8)];
      else    bfr[nf] = *(const bf16x8*)&yT[row * 260 + kc + lc * 8];
    }
#pragma unroll
    for (int mf = 0; mf < 4; ++mf) {
      int row = wm * 64 + mf * 16 + lr;
      af[mf] = *(const bf16x8*)&As[row * 32 + ((lc ^ (row & 3)) * 8)];
    }
#pragma unroll
    for (int mf = 0; mf < 4; ++mf)
#pragma unroll
      for (int nf = 0; nf < 4; ++nf)
        acc[mf][nf] = __builtin_amdgcn_mfma_f32_16x16x32_bf16(af[mf], bfr[nf], acc[mf][nf], 0, 0, 0);
    if (xk) {
      bf16x8 af2[4];
#pragma unroll
      for (int mf = 0; mf < 4; ++mf) {
        int row = wm * 64 + mf * 16 + lr;
        af2[mf] = *(const bf16x8*)&As2[row * 32 + ((lc ^ (row & 3)) * 8)];
      }
#pragma unroll
      for (int mf = 0; mf < 4; ++mf)
#pragma unroll
        for (int nf = 0; nf < 4; ++nf)
          acc2[mf][nf] = __builtin_amdgcn_mfma_f32_16x16x32_bf16(af2[mf], bfr[nf], acc2[mf][nf], 0, 0, 0);
    }
    __syncthreads();
  }

  // epilogue: out = sig(gpre)*res + (1-sig)*y
#pragma unroll
  for (int mf = 0; mf < 4; ++mf)
#pragma unroll
    for (int nf = 0; nf < 4; ++nf) {
      f32x4 g4 = acc[mf][nf], r4 = acc2[mf][nf];
      int m = wm * 64 + mf * 16 + lc * 4;
      int n = wn * 64 + nf * 16 + lr;
      U16x4 yv = *(const U16x4*)&yT[n * 260 + m];
      const u16* yp = (const u16*)&yv;
      float* p = out + (int64_t)b * 256 * 4096 + (int64_t)m * 4096 + l0 + n;
#pragma unroll
      for (int r = 0; r < 4; ++r) {
        float g = 1.f / (1.f + __expf(-g4[r]));
        p[(int64_t)r * 4096] = g * r4[r] + (1.f - g) * bf2f(yp[r]);
      }
    }
}

// ---------------------------------------------------------------------------
// merged prep: all weight converts + zero page in ONE kernel
// ---------------------------------------------------------------------------
__global__ void k_prep(const float* __restrict__ wqkv, const float* __restrict__ wmod,
                       const float* __restrict__ wgate, const float* __restrict__ wres,
                       u16* __restrict__ Wa, u16* __restrict__ Wb,
                       u16* __restrict__ Wg, u16* __restrict__ Wr,
                       uint32_t* __restrict__ zpage) {
  int bid = blockIdx.x, t = threadIdx.x;
  if (bid < 6912) {                           // Wa: 768 x (9*256)
    int idx = bid * 256 + t;
    if (idx < 768 * 2304) {
      int oc = idx / 2304, r = idx % 2304;
      int tap = r >> 8, ic = r & 255;
      Wa[idx] = f2bf(wqkv[((oc * 256 + ic) * 3 + tap / 3) * 3 + tap % 3]);
    }
  } else if (bid < 8448) {                    // Wb: 512 x (3*256)
    int idx = (bid - 6912) * 256 + t;
    if (idx < 512 * 768) {
      int oc = idx / 768, r = idx % 768;
      int tap = r >> 8, ic = r & 255;
      Wb[idx] = f2bf(wmod[(oc * 256 + ic) * 3 + tap]);
    }
  } else if (bid < 8960) {                    // Wg: 256 x 512
    int idx = (bid - 8448) * 256 + t;
    if (idx < 131072) Wg[idx] = f2bf(wgate[idx]);
  } else if (bid < 9216) {                    // Wr: 256 x 256
    int idx = (bid - 8960) * 256 + t;
    if (idx < 65536) Wr[idx] = f2bf(wres[idx]);
  } else {
    if (t < 64) zpage[t] = 0u;
  }
}

// ---------------------------------------------------------------------------
// x (B,256,4096) f32 -> ycatT[b][l][256+c] bf16 (x part of concat buffer)
// ---------------------------------------------------------------------------
__global__ __launch_bounds__(256) void k_xT(const float* __restrict__ x, u16* __restrict__ ycat) {
  __shared__ float tile[64 * 68];
  int b = blockIdx.z, c0 = blockIdx.y * 64, l0 = blockIdx.x * 64;
  int t = threadIdx.x;
  int cc = t >> 2, part = t & 3;
  const float* xp = x + ((int64_t)(b * 256 + c0 + cc)) * 4096 + l0 + part * 16;
#pragma unroll
  for (int j = 0; j < 4; ++j) {
    F4 v = *(const F4*)(xp + j * 4);
    float* tp = &tile[cc * 68 + part * 16 + j * 4];
    tp[0] = v.x; tp[1] = v.y; tp[2] = v.z; tp[3] = v.w;
  }
  __syncthreads();
  int l = t >> 2;
  u16* op = ycat + ((int64_t)b * 4096 + l0 + l) * 512 + 256 + c0 + part * 16;
  __align__(16) u16 tmp[16];
#pragma unroll
  for (int j = 0; j < 16; ++j) tmp[j] = f2bf(tile[(part * 16 + j) * 68 + l]);
  *(V16*)(op) = *(V16*)&tmp[0];
  *(V16*)(op + 8) = *(V16*)&tmp[8];
}

// sum 64 partials per channel -> 1/S
__global__ void k_statsB64(const float* __restrict__ part, float* __restrict__ inv) {
  int idx = blockIdx.x * 256 + threadIdx.x;   // 4096 channels (b*512+m)
  float S = 0.f;
#pragma unroll
  for (int s = 0; s < 64; ++s) S += part[(int64_t)idx * 64 + s];
  inv[idx] = 1.0f / S;
}

// softmax over d of (sum split-K partials)*invSq[c]*invSk[d]*(1/16)
__global__ __launch_bounds__(256) void k_softmax_attn(
    const float* __restrict__ sc, const float* __restrict__ invS,
    u16* __restrict__ ma, int nsplit, int64_t splitOff) {
  int c = blockIdx.x, b = blockIdx.y;
  int64_t base = ((int64_t)b * 256 + c) * 256;
  int t = threadIdx.x;
  float z = 0.f;
  for (int s = 0; s < nsplit; ++s) z += sc[(int64_t)s * splitOff + base + t];
  float iq = invS[(int64_t)b * 512 + c];
  float ik = invS[(int64_t)b * 512 + 256 + t];
  z *= iq * ik * 0.0625f;
  __shared__ float red[256];
  red[t] = z; __syncthreads();
  for (int s = 128; s > 0; s >>= 1) { if (t < s) red[t] = fmaxf(red[t], red[t + s]); __syncthreads(); }
  float M = red[0]; __syncthreads();
  float p = __expf(z - M);
  red[t] = p; __syncthreads();
  for (int s = 128; s > 0; s >>= 1) { if (t < s) red[t] += red[t + s]; __syncthreads(); }
  ma[base + t] = f2bf(p / red[0]);
}

// ---------------------------------------------------------------------------
extern "C" void kernel_launch(void* const* d_in, const int* in_sizes, int n_in,
                              void* d_out, int out_size, void* d_ws, size_t ws_size,
                              hipStream_t stream) {
  (void)in_sizes; (void)n_in; (void)out_size; (void)ws_size;
  const float* x      = (const float*)d_in[0];
  const float* w_qkv  = (const float*)d_in[1];
  const float* w_mod  = (const float*)d_in[2];
  const float* w_res  = (const float*)d_in[3];
  const float* w_gate = (const float*)d_in[4];
  float* out = (float*)d_out;

  char* p = (char*)d_ws;
  auto take = [&](size_t n) { void* r = (void*)p; p += (n + 255) & ~(size_t)255; return r; };
  u16*    zpage  = (u16*)take(256);        // zero page for masked conv taps
  u16*    qkvT   = (u16*)take(50331648);   // [b][l][768] bf16 (q|k|v)
  u16*    ycatT  = (u16*)take(33554432);   // [b][l][512] bf16 (x in cols 256+)
  u16*    eT     = (u16*)take(33554432);   // [b][512ch][l] bf16 (e_q|e_k)
  float*  scores = (float*)take(16777216); // [8 splits][b][c][d] f32
  u16*    mattn  = (u16*)take(1048576);    // [b][c][d] bf16
  float*  partS  = (float*)take(1048576);  // [b*512+ch][64] partial sums
  float*  invS   = (float*)take(16384);    // [b*512+ch] 1/S
  u16*    Wa     = (u16*)take(3538944);    // 768 x 2304
  u16*    Wb     = (u16*)take(786432);     // 512 x 768
  u16*    Wg     = (u16*)take(262144);     // 256 x 512
  u16*    Wr     = (u16*)take(131072);     // 256 x 256

  k_prep<<<9217, 256, 0, stream>>>(w_qkv, w_mod, w_gate, w_res,
                                   Wa, Wb, Wg, Wr, (uint32_t*)zpage);
  k_xT<<<dim3(64, 4, 8), 256, 0, stream>>>(x, ycatT);

  // qkv = conv2d(x, w_qkv): M=768 N=4096 K=9*256 -> qkvT bf16
  gemmOv_bf16<2, 6><<<512, 512, 0, stream>>>(
      Wa, ycatT + 256, qkvT,
      2304, 512, (int64_t)4096 * 512,
      768, (int64_t)4096 * 768, 4, zpage);

  // mod = conv1d(v, w_mod) FUSED with e = exp(-relu(q*mod)) -> eT + partS
  gemmOv_bf16<1, 8, 1><<<256, 512, 0, stream>>>(
      Wb, qkvT + 512, nullptr,
      768, 768, (int64_t)4096 * 768,
      0, 0, 2, zpage,
      qkvT, eT, partS);

  k_statsB64<<<16, 256, 0, stream>>>(partS, invS);

  // scores'[c][d] = sum_l e_q[c,l]*e_k[d,l]: M=256 N=256 K=4096, split-K x8
  gemm_scores<<<dim3(2, 2, 64), 256, 0, stream>>>(
      eT, eT + (int64_t)256 * 4096, scores,
      4096, (int64_t)512 * 4096,
      4096, (int64_t)512 * 4096,
      256, (int64_t)256 * 256,
      8, 512, (int64_t)8 * 256 * 256);

  k_softmax_attn<<<dim3(256, 8), 256, 0, stream>>>(
      scores, invS, mattn, 8, (int64_t)8 * 256 * 256);

  // fused tail: y = mattn@v -> gate/res/blend -> out
  k_tail<<<dim3(32, 8), 512, 0, stream>>>(mattn, qkvT, ycatT, Wg, Wr, out);
}